// Round 19
// baseline (434.479 us; speedup 1.0000x reference)
//
#include <hip/hip_runtime.h>
#include <hip/hip_bf16.h>
#include <cstddef>

// ---------------------------------------------------------------------------
// TriangularSelfAttentionBlock R18: pairfuse single-buffer (32KB LDS ->
// 4 blocks/CU, inter-block TLP hides DMA waits). Rest identical to R15/R17.
// L=512, SEQ_D=1024, PAIR_D=128, H=32, HW=32, INNER=64
// ---------------------------------------------------------------------------

#define L 512
#define SEQ_D 1024
#define PAIR_D 128
#define NH 32
#define HW 32

typedef short bf16x8 __attribute__((ext_vector_type(8)));
typedef float f32x4 __attribute__((ext_vector_type(4)));
typedef unsigned short ushort_t;

__device__ inline float wred_sum(float v) {
#pragma unroll
  for (int off = 32; off; off >>= 1) v += __shfl_xor(v, off, 64);
  return v;
}
// f32 -> bf16 (RNE) packed pair via HW instruction (a low, b high)
__device__ inline unsigned pk2(float a, float b) {
  unsigned r;
  asm("v_cvt_pk_bf16_f32 %0, %1, %2" : "=v"(r) : "v"(a), "v"(b));
  return r;
}
__device__ inline ushort_t bf1(float a) {
  unsigned r;
  asm("v_cvt_pk_bf16_f32 %0, %1, %2" : "=v"(r) : "v"(a), "v"(0.f));
  return (ushort_t)r;
}
__device__ inline float bfl(unsigned u) { return __uint_as_float(u << 16); }
__device__ inline float bfh(unsigned u) { return __uint_as_float(u & 0xffff0000u); }
__device__ inline float bfu(ushort_t u) { return __uint_as_float((unsigned)u << 16); }

// swizzled byte offset for [row][256B] LDS tiles
#define SWZ(row, kb) ((((row)) << 8) + ((kb) ^ (((row)&7) << 4)))
// swizzled byte offset for [row][128B] LDS tiles
#define SWZ64(row, kb) ((((row)) << 7) + ((kb) ^ (((row)&7) << 4)))

// ---- async stage 32KB weight tile (128 rows x 256B swizzled) via
// global_load_lds: linear LDS dest, inverse-swizzled per-lane global source.
__device__ __forceinline__ void stage_w32k(const ushort_t* __restrict__ src,
                                           int row_stride, int col_off,
                                           char* lds, int w, int l) {
#pragma unroll
  for (int i = 0; i < 8; ++i) {
    const int o = w * 8192 + i * 1024 + l * 16;
    const int row = o >> 8;
    const int kb = (o & 255) ^ (((row) & 7) << 4);
    const ushort_t* g = src + (size_t)row * row_stride + col_off + (kb >> 1);
    __builtin_amdgcn_global_load_lds(
        (const __attribute__((address_space(1))) unsigned int*)g,
        (__attribute__((address_space(3))) unsigned int*)(lds + w * 8192 + i * 1024),
        16, 0, 0);
  }
}

// ---------------- fused f32->bf16 weight conversion + concat bias ----------
// Wp1/Wp2 written with each 128-wide k-chunk PERMUTED so GEMM fragments match
// the natural C-layout of the previous GEMM output. Blocks >= 6792 build the
// concatenated qkv|gate bias vector.
__global__ __launch_bounds__(256) void cvt9_kernel(
    const float* __restrict__ s0, ushort_t* __restrict__ d0,
    const float* __restrict__ s1, ushort_t* __restrict__ d1,
    const float* __restrict__ s2, ushort_t* __restrict__ d2,
    const float* __restrict__ s3, ushort_t* __restrict__ d3,
    const float* __restrict__ s4, ushort_t* __restrict__ d4,
    const float* __restrict__ s5, ushort_t* __restrict__ d5,
    const float* __restrict__ s6, ushort_t* __restrict__ d6,
    const float* __restrict__ s7, ushort_t* __restrict__ d7,
    const float* __restrict__ s8, ushort_t* __restrict__ d8,
    const float* __restrict__ bgate, float* __restrict__ bias_cat) {
  const int b = blockIdx.x;
  if (b >= 6792) {
    const int i = (b - 6792) * 256 + threadIdx.x;
    bias_cat[i] = (i < 3072) ? 0.f : bgate[i - 3072];
    return;
  }
  if (b >= 6728) {
    const float* s; ushort_t* d; int base, rowlen;
    if (b < 6760) { s = s7; d = d7; base = b - 6728; rowlen = 128; }
    else          { s = s8; d = d8; base = b - 6760; rowlen = 512; }
    const int i = base * 256 + threadIdx.x;
    float4 a = ((const float4*)s)[2 * i], c = ((const float4*)s)[2 * i + 1];
    const int fe = i * 8;
    const int row = fe / rowlen;
    const int fk = fe % rowlen;
    const int ch = fk >> 7, k0 = fk & 127;
    const int kk = k0 >> 5, r0 = k0 & 31;
    const int hi = (r0 >> 4) & 1, g16a = (r0 >> 2) & 3;
    const int p1 = kk * 32 + g16a * 8 + hi * 4;
    ushort_t* dst = d + (size_t)row * rowlen + ch * 128;
    uint2 w1; w1.x = pk2(a.x, a.y); w1.y = pk2(a.z, a.w);
    uint2 w2; w2.x = pk2(c.x, c.y); w2.y = pk2(c.z, c.w);
    *(uint2*)(dst + p1) = w1;
    *(uint2*)(dst + p1 + 8) = w2;
    return;
  }
  const float* s; ushort_t* d; int base;
  if (b < 1536)      { s = s0; d = d0; base = b; }
  else if (b < 2048) { s = s1; d = d1; base = b - 1536; }
  else if (b < 2560) { s = s2; d = d2; base = b - 2048; }
  else if (b < 4608) { s = s3; d = d3; base = b - 2560; }
  else if (b < 6656) { s = s4; d = d4; base = b - 4608; }
  else if (b < 6720) { s = s5; d = d5; base = b - 6656; }
  else               { s = s6; d = d6; base = b - 6720; }
  const int i = base * 256 + threadIdx.x;
  float4 a = ((const float4*)s)[2 * i], c = ((const float4*)s)[2 * i + 1];
  uint4 w;
  w.x = pk2(a.x, a.y); w.y = pk2(a.z, a.w);
  w.z = pk2(c.x, c.y); w.w = pk2(c.z, c.w);
  ((uint4*)d)[i] = w;
}

// ---------------- LayerNorm 1024 -> bf16 out -------------------------------
__global__ __launch_bounds__(256) void ln1024b_kernel(
    const float* __restrict__ in, const float* __restrict__ g,
    const float* __restrict__ b, ushort_t* __restrict__ out) {
  const int row = blockIdx.x;
  const int tid = threadIdx.x;
  float4 v = ((const float4*)(in + (size_t)row * SEQ_D))[tid];
  float s = v.x + v.y + v.z + v.w;
  float s2 = v.x * v.x + v.y * v.y + v.z * v.z + v.w * v.w;
  __shared__ float red[8];
  const int lane = tid & 63, wid = tid >> 6;
  s = wred_sum(s);
  s2 = wred_sum(s2);
  if (lane == 0) { red[wid] = s; red[4 + wid] = s2; }
  __syncthreads();
  s = red[0] + red[1] + red[2] + red[3];
  s2 = red[4] + red[5] + red[6] + red[7];
  const float mean = s * (1.0f / SEQ_D);
  const float var = s2 * (1.0f / SEQ_D) - mean * mean;
  const float rstd = rsqrtf(var + 1e-5f);
  float4 gv = ((const float4*)g)[tid];
  float4 bv = ((const float4*)b)[tid];
  const float o0 = (v.x - mean) * rstd * gv.x + bv.x;
  const float o1 = (v.y - mean) * rstd * gv.y + bv.y;
  const float o2 = (v.z - mean) * rstd * gv.z + bv.z;
  const float o3 = (v.w - mean) * rstd * gv.w + bv.w;
  uint2 pkd; pkd.x = pk2(o0, o1); pkd.y = pk2(o2, o3);
  ((uint2*)(out + (size_t)row * SEQ_D))[tid] = pkd;
}

// ---------------- MFMA GEMM: C[M][N] = A[M][K](bf16) @ B[N][K]^T(bf16) -----
template <int BIAS, int RELU, int RES, int OBF16>
__global__ __launch_bounds__(256, 2) void gemm_mfma_kernel(
    const ushort_t* __restrict__ A, const ushort_t* __restrict__ B,
    const float* __restrict__ bias, const float* __restrict__ res,
    float* __restrict__ C, ushort_t* __restrict__ Cb, int M, int N, int K) {
  __shared__ __align__(16) char smem[24576];
  char* Ab = smem;
  char* Bb = smem + 8192;
  const int tid = threadIdx.x;
  const int l = tid & 63, w = tid >> 6;
  const int wr = w >> 1, wc = w & 1;
  const int lane16 = l & 15, g16 = l >> 4;
  const int bm = blockIdx.y * 64, bn = blockIdx.x * 128;
  const f32x4 fz = {0.f, 0.f, 0.f, 0.f};
  f32x4 acc[4][2];
#pragma unroll
  for (int i = 0; i < 4; ++i)
#pragma unroll
    for (int j = 0; j < 2; ++j) acc[i][j] = fz;

  for (int k0 = 0; k0 < K; k0 += 64) {
    __syncthreads();
#pragma unroll
    for (int u = 0; u < 2; ++u) {
      const int slot = u * 256 + tid;
      const int row = slot >> 3, sl = slot & 7;
      bf16x8 v = *(const bf16x8*)(A + (size_t)(bm + row) * K + k0 + sl * 8);
      *(bf16x8*)(Ab + SWZ64(row, sl * 16)) = v;
    }
#pragma unroll
    for (int u = 0; u < 4; ++u) {
      const int slot = u * 256 + tid;
      const int row = slot >> 3, sl = slot & 7;
      bf16x8 v = *(const bf16x8*)(B + (size_t)(bn + row) * K + k0 + sl * 8);
      *(bf16x8*)(Bb + SWZ64(row, sl * 16)) = v;
    }
    __syncthreads();
#pragma unroll
    for (int kk = 0; kk < 2; ++kk) {
      const int kb = kk * 64 + g16 * 16;
      bf16x8 af[2], bf[4];
#pragma unroll
      for (int rb = 0; rb < 2; ++rb) {
        const int row = wr * 32 + rb * 16 + lane16;
        af[rb] = *(const bf16x8*)(Ab + SWZ64(row, kb));
      }
#pragma unroll
      for (int cb = 0; cb < 4; ++cb) {
        const int row = wc * 64 + cb * 16 + lane16;
        bf[cb] = *(const bf16x8*)(Bb + SWZ64(row, kb));
      }
#pragma unroll
      for (int cb = 0; cb < 4; ++cb)
#pragma unroll
        for (int rb = 0; rb < 2; ++rb)
          acc[cb][rb] = __builtin_amdgcn_mfma_f32_16x16x32_bf16(
              bf[cb], af[rb], acc[cb][rb], 0, 0, 0);
    }
  }
#pragma unroll
  for (int cb = 0; cb < 4; ++cb) {
    const int col0 = bn + wc * 64 + cb * 16 + g16 * 4;
    float4 bi = make_float4(0.f, 0.f, 0.f, 0.f);
    if (BIAS) bi = *(const float4*)(bias + col0);
#pragma unroll
    for (int rb = 0; rb < 2; ++rb) {
      const int row = bm + wr * 32 + rb * 16 + lane16;
      f32x4 v = acc[cb][rb];
      v[0] += bi.x; v[1] += bi.y; v[2] += bi.z; v[3] += bi.w;
      if (RELU) {
        v[0] = fmaxf(v[0], 0.f); v[1] = fmaxf(v[1], 0.f);
        v[2] = fmaxf(v[2], 0.f); v[3] = fmaxf(v[3], 0.f);
      }
      if (RES) {
        const float4 r4 = *(const float4*)(res + (size_t)row * N + col0);
        v[0] += r4.x; v[1] += r4.y; v[2] += r4.z; v[3] += r4.w;
      }
      if (OBF16) {
        uint2 pkd; pkd.x = pk2(v[0], v[1]); pkd.y = pk2(v[2], v[3]);
        *(uint2*)(Cb + (size_t)row * N + col0) = pkd;
      } else {
        float4 o4; o4.x = v[0]; o4.y = v[1]; o4.z = v[2]; o4.w = v[3];
        *(float4*)(C + (size_t)row * N + col0) = o4;
      }
    }
  }
}

// ---------------- PairToSequence via MFMA (bf16 biasT out) -----------------
__global__ __launch_bounds__(256) void p2s_mfma_kernel(
    const float* __restrict__ pair, const float* __restrict__ g,
    const float* __restrict__ b, const float* __restrict__ W,
    ushort_t* __restrict__ biasTb) {
  __shared__ __align__(16) char pnb[32768];
  __shared__ __align__(16) char wls[8192];
  const int tid = threadIdx.x;
  const int l = tid & 63, w = tid >> 6;
  const int lane16 = l & 15, g16 = l >> 4;
  const size_t r0 = (size_t)blockIdx.x * 128;
  const int i_idx = (int)(r0 >> 9), j0 = (int)(r0 & 511);
#pragma unroll
  for (int u = 0; u < 2; ++u) {
    const int slot = u * 256 + tid;
    const int row = slot >> 4, sl = slot & 15;
    const float4 v0 = *(const float4*)(W + (size_t)row * 128 + sl * 8);
    const float4 v1 = *(const float4*)(W + (size_t)row * 128 + sl * 8 + 4);
    uint4 wv; wv.x = pk2(v0.x, v0.y); wv.y = pk2(v0.z, v0.w);
    wv.z = pk2(v1.x, v1.y); wv.w = pk2(v1.z, v1.w);
    *(uint4*)(wls + SWZ(row, sl * 16)) = wv;
  }
  {
    const int l32 = tid & 31, rg = tid >> 5;
    const float4 gv = *(const float4*)(g + l32 * 4);
    const float4 bv = *(const float4*)(b + l32 * 4);
#pragma unroll
    for (int it = 0; it < 16; ++it) {
      const int r = it * 8 + rg;
      const float4 v = *(const float4*)(pair + (r0 + r) * 128 + l32 * 4);
      float s = v.x + v.y + v.z + v.w;
      float s2 = v.x * v.x + v.y * v.y + v.z * v.z + v.w * v.w;
#pragma unroll
      for (int off = 1; off < 32; off <<= 1) {
        s += __shfl_xor(s, off, 64);
        s2 += __shfl_xor(s2, off, 64);
      }
      const float mean = s * (1.0f / 128.0f);
      const float rstd = rsqrtf(s2 * (1.0f / 128.0f) - mean * mean + 1e-5f);
      const float n0 = (v.x - mean) * rstd * gv.x + bv.x;
      const float n1 = (v.y - mean) * rstd * gv.y + bv.y;
      const float n2 = (v.z - mean) * rstd * gv.z + bv.z;
      const float n3 = (v.w - mean) * rstd * gv.w + bv.w;
      uint2 pkd; pkd.x = pk2(n0, n1); pkd.y = pk2(n2, n3);
      *(uint2*)(pnb + SWZ(r, l32 * 8)) = pkd;
    }
  }
  __syncthreads();
  const f32x4 fz = {0.f, 0.f, 0.f, 0.f};
  f32x4 a2[2][2];
#pragma unroll
  for (int i = 0; i < 2; ++i)
#pragma unroll
    for (int j = 0; j < 2; ++j) a2[i][j] = fz;
#pragma unroll
  for (int kk = 0; kk < 4; ++kk) {
    bf16x8 wf[2], pf[2];
#pragma unroll
    for (int hb = 0; hb < 2; ++hb)
      wf[hb] = *(const bf16x8*)(wls + SWZ(hb * 16 + lane16, kk * 64 + g16 * 16));
#pragma unroll
    for (int rb = 0; rb < 2; ++rb)
      pf[rb] = *(const bf16x8*)(pnb + SWZ(w * 32 + rb * 16 + lane16, kk * 64 + g16 * 16));
#pragma unroll
    for (int hb = 0; hb < 2; ++hb)
#pragma unroll
      for (int rb = 0; rb < 2; ++rb)
        a2[hb][rb] = __builtin_amdgcn_mfma_f32_16x16x32_bf16(
            wf[hb], pf[rb], a2[hb][rb], 0, 0, 0);
  }
#pragma unroll
  for (int hb = 0; hb < 2; ++hb)
#pragma unroll
    for (int rb = 0; rb < 2; ++rb) {
      const int j = j0 + w * 32 + rb * 16 + lane16;
#pragma unroll
      for (int qq = 0; qq < 4; ++qq) {
        const int hh = hb * 16 + g16 * 4 + qq;
        biasTb[((size_t)hh * 512 + i_idx) * 512 + j] = bf1(a2[hb][rb][qq]);
      }
    }
}

// ---------------- fused attention + gate: ob = sig(g)*softmax(S)V ----------
// tb row layout: [qkv 3072 | gate 1024], stride 4096 bf16.
__global__ __launch_bounds__(256) void attn_kernel(
    const ushort_t* __restrict__ tb, const ushort_t* __restrict__ biasTb,
    ushort_t* __restrict__ ob) {
  __shared__ __align__(16) ushort_t Vt[32][80];
  const int tid = threadIdx.x;
  const int l = tid & 63, wq = tid >> 6;
  const int lane16 = l & 15, g16 = l >> 4;
  const int h = blockIdx.y;
  const int q = blockIdx.x * 64 + wq * 16 + lane16;
  const float scale = 0.17677669529663689f;
  const bf16x8 qf = *(const bf16x8*)(tb + (size_t)q * 4096 + h * 96 + g16 * 8);
  const ushort_t* brow = biasTb + ((size_t)h * 512 + q) * 512;
  float m = -3e38f, lsum = 0.f;
  const f32x4 fz = {0.f, 0.f, 0.f, 0.f};
  f32x4 accp[2] = {fz, fz};
  for (int kt = 0; kt < 512; kt += 64) {
    {
      const int kr = tid >> 2, cc = tid & 3;
      bf16x8 vv = *(const bf16x8*)(tb + (size_t)(kt + kr) * 4096 + h * 96 + 64 + cc * 8);
#pragma unroll
      for (int u = 0; u < 8; ++u) Vt[cc * 8 + u][kr] = (ushort_t)vv[u];
    }
    __syncthreads();
    f32x4 st[4];
#pragma unroll
    for (int kb = 0; kb < 4; ++kb) {
      const bf16x8 kf = *(const bf16x8*)(
          tb + (size_t)(kt + kb * 16 + lane16) * 4096 + h * 96 + 32 + g16 * 8);
      st[kb] = __builtin_amdgcn_mfma_f32_16x16x32_bf16(kf, qf, fz, 0, 0, 0);
      const ushort4 bv = *(const ushort4*)(brow + kt + kb * 16 + g16 * 4);
      st[kb][0] = st[kb][0] * scale + bfu(bv.x);
      st[kb][1] = st[kb][1] * scale + bfu(bv.y);
      st[kb][2] = st[kb][2] * scale + bfu(bv.z);
      st[kb][3] = st[kb][3] * scale + bfu(bv.w);
    }
    float tm = st[0][0];
#pragma unroll
    for (int kb = 0; kb < 4; ++kb)
#pragma unroll
      for (int qq = 0; qq < 4; ++qq) tm = fmaxf(tm, st[kb][qq]);
    tm = fmaxf(tm, __shfl_xor(tm, 16, 64));
    tm = fmaxf(tm, __shfl_xor(tm, 32, 64));
    const float mn = fmaxf(m, tm);
    const float corr = __expf(m - mn);
    m = mn;
    lsum *= corr;
#pragma unroll
    for (int ct = 0; ct < 2; ++ct) {
      accp[ct][0] *= corr; accp[ct][1] *= corr;
      accp[ct][2] *= corr; accp[ct][3] *= corr;
    }
#pragma unroll
    for (int kb = 0; kb < 4; ++kb)
#pragma unroll
      for (int qq = 0; qq < 4; ++qq) {
        const float e = __expf(st[kb][qq] - mn);
        st[kb][qq] = e;
        lsum += e;
      }
    const int src0 = lane16 + ((l & 16) << 1);
    const int src1 = src0 + 16;
    const bool hi = (l & 32) != 0;
#pragma unroll
    for (int kk = 0; kk < 2; ++kk) {
      float lo4[4], hi4[4];
#pragma unroll
      for (int qq = 0; qq < 4; ++qq) {
        const float a0 = __shfl(st[kk * 2][qq], src0, 64);
        const float a1 = __shfl(st[kk * 2][qq], src1, 64);
        const float b0 = __shfl(st[kk * 2 + 1][qq], src0, 64);
        const float b1 = __shfl(st[kk * 2 + 1][qq], src1, 64);
        lo4[qq] = hi ? b0 : a0;
        hi4[qq] = hi ? b1 : a1;
      }
      uint4 pu;
      pu.x = pk2(lo4[0], lo4[1]); pu.y = pk2(lo4[2], lo4[3]);
      pu.z = pk2(hi4[0], hi4[1]); pu.w = pk2(hi4[2], hi4[3]);
      bf16x8 pf;
      __builtin_memcpy(&pf, &pu, 16);
#pragma unroll
      for (int ct = 0; ct < 2; ++ct) {
        const bf16x8 vf = *(const bf16x8*)&Vt[ct * 16 + lane16][kk * 32 + g16 * 8];
        accp[ct] = __builtin_amdgcn_mfma_f32_16x16x32_bf16(vf, pf, accp[ct], 0, 0, 0);
      }
    }
    __syncthreads();
  }
  lsum += __shfl_xor(lsum, 16, 64);
  lsum += __shfl_xor(lsum, 32, 64);
  const float inv = 1.0f / lsum;
#pragma unroll
  for (int ct = 0; ct < 2; ++ct) {
    const int col = h * 32 + ct * 16 + g16 * 4;
    const ushort4 gv = *(const ushort4*)(tb + (size_t)q * 4096 + 3072 + col);
    float4 o4;
    o4.x = accp[ct][0] * inv * (1.0f / (1.0f + __expf(-bfu(gv.x))));
    o4.y = accp[ct][1] * inv * (1.0f / (1.0f + __expf(-bfu(gv.y))));
    o4.z = accp[ct][2] * inv * (1.0f / (1.0f + __expf(-bfu(gv.z))));
    o4.w = accp[ct][3] * inv * (1.0f / (1.0f + __expf(-bfu(gv.w))));
    uint2 pkd; pkd.x = pk2(o4.x, o4.y); pkd.y = pk2(o4.z, o4.w);
    *(uint2*)(ob + (size_t)q * SEQ_D + col) = pkd;
  }
}

// ---------------- fused SequenceToPair + pair MLP (rb=2, single 32KB W
// buffer, 4 blocks/CU; shuffle-free via k-permuted W1/W2) -------------------
__global__ __launch_bounds__(256, 3) void pairfuse64_kernel(
    const float* __restrict__ spb, const ushort_t* __restrict__ Wspob,
    const float* __restrict__ bspo, const float* __restrict__ pairw,
    const float* __restrict__ lng, const float* __restrict__ lnb,
    const ushort_t* __restrict__ Wp1b, const float* __restrict__ bp1,
    const ushort_t* __restrict__ Wp2b, const float* __restrict__ bp2,
    float* __restrict__ pout) {
  __shared__ __align__(16) char Wbuf[32768];
  char* buf = Wbuf;
  const int tid = threadIdx.x;
  const int l = tid & 63, w = tid >> 6;
  const int lane16 = l & 15, g16 = l >> 4;
  const size_t r0 = (size_t)blockIdx.x * 128;
  const int i_idx = (int)(r0 >> 9), j0 = (int)(r0 & 511);
  size_t grow[2];
  grow[0] = r0 + w * 32 + lane16;
  grow[1] = grow[0] + 16;

  // ---- issue Wspo -> buf (async; drained at first sync) ----
  stage_w32k(Wspob, 128, 0, buf, w, l);

  // ---- build X A-frags in registers: X = [qh*kh | qh-kh] (overlaps DMA) ---
  bf16x8 xf[2][4];
  {
    const float* krow = spb + (size_t)i_idx * 128 + 64;
#pragma unroll
    for (int rb = 0; rb < 2; ++rb) {
      const float* qrow = spb + (size_t)(j0 + w * 32 + rb * 16 + lane16) * 128;
#pragma unroll
      for (int kk = 0; kk < 4; ++kk) {
        const int c = ((kk & 1) << 5) + g16 * 8;
        const float4 q0 = *(const float4*)(qrow + c);
        const float4 q1 = *(const float4*)(qrow + c + 4);
        const float4 k0 = *(const float4*)(krow + c);
        const float4 k1 = *(const float4*)(krow + c + 4);
        uint4 u;
        if (kk < 2) {
          u.x = pk2(q0.x * k0.x, q0.y * k0.y);
          u.y = pk2(q0.z * k0.z, q0.w * k0.w);
          u.z = pk2(q1.x * k1.x, q1.y * k1.y);
          u.w = pk2(q1.z * k1.z, q1.w * k1.w);
        } else {
          u.x = pk2(q0.x - k0.x, q0.y - k0.y);
          u.y = pk2(q0.z - k0.z, q0.w - k0.w);
          u.z = pk2(q1.x - k1.x, q1.y - k1.y);
          u.w = pk2(q1.z - k1.z, q1.w - k1.w);
        }
        __builtin_memcpy(&xf[rb][kk], &u, 16);
      }
    }
  }
  __syncthreads();  // Wspo landed

  // ---- GEMM0: acc[rb][cb] = X @ Wspo^T ----
  const f32x4 fz = {0.f, 0.f, 0.f, 0.f};
  f32x4 acc[2][8];
#pragma unroll
  for (int rb = 0; rb < 2; ++rb)
#pragma unroll
    for (int cb = 0; cb < 8; ++cb) acc[rb][cb] = fz;
#pragma unroll
  for (int cb = 0; cb < 8; ++cb) {
#pragma unroll
    for (int kk = 0; kk < 4; ++kk) {
      const bf16x8 wf = *(const bf16x8*)(
          buf + SWZ(cb * 16 + lane16, kk * 64 + g16 * 16));
      acc[0][cb] = __builtin_amdgcn_mfma_f32_16x16x32_bf16(wf, xf[0][kk], acc[0][cb], 0, 0, 0);
      acc[1][cb] = __builtin_amdgcn_mfma_f32_16x16x32_bf16(wf, xf[1][kk], acc[1][cb], 0, 0, 0);
    }
  }
  __syncthreads();  // GEMM0 LDS reads done
  stage_w32k(Wp1b, 128, 0, buf, w, l);  // W1[0] -> buf (async)

  // ---- P = acc + bspo + pair; LN stats in-wave (overlaps W1[0] DMA) ----
  uint2 Ppk[2][8];
  bf16x8 pnf[2][4];
#pragma unroll
  for (int rb = 0; rb < 2; ++rb) {
    float s = 0.f, s2 = 0.f;
#pragma unroll
    for (int cb = 0; cb < 8; ++cb) {
      const int col0 = cb * 16 + g16 * 4;
      const float4 bs = *(const float4*)(bspo + col0);
      const float4 pw = *(const float4*)(pairw + grow[rb] * 128 + col0);
      acc[rb][cb][0] += bs.x + pw.x; acc[rb][cb][1] += bs.y + pw.y;
      acc[rb][cb][2] += bs.z + pw.z; acc[rb][cb][3] += bs.w + pw.w;
      s += acc[rb][cb][0] + acc[rb][cb][1] + acc[rb][cb][2] + acc[rb][cb][3];
      s2 += acc[rb][cb][0] * acc[rb][cb][0] + acc[rb][cb][1] * acc[rb][cb][1] +
            acc[rb][cb][2] * acc[rb][cb][2] + acc[rb][cb][3] * acc[rb][cb][3];
      Ppk[rb][cb].x = pk2(acc[rb][cb][0], acc[rb][cb][1]);
      Ppk[rb][cb].y = pk2(acc[rb][cb][2], acc[rb][cb][3]);
    }
    s += __shfl_xor(s, 16, 64);  s += __shfl_xor(s, 32, 64);
    s2 += __shfl_xor(s2, 16, 64); s2 += __shfl_xor(s2, 32, 64);
    const float mean = s * (1.0f / 128.0f);
    const float rstd = rsqrtf(s2 * (1.0f / 128.0f) - mean * mean + 1e-5f);
    uint2 pnpk[8];
#pragma unroll
    for (int cb = 0; cb < 8; ++cb) {
      const int col0 = cb * 16 + g16 * 4;
      const float4 gv = *(const float4*)(lng + col0);
      const float4 bv = *(const float4*)(lnb + col0);
      const float n0 = (acc[rb][cb][0] - mean) * rstd * gv.x + bv.x;
      const float n1 = (acc[rb][cb][1] - mean) * rstd * gv.y + bv.y;
      const float n2 = (acc[rb][cb][2] - mean) * rstd * gv.z + bv.z;
      const float n3 = (acc[rb][cb][3] - mean) * rstd * gv.w + bv.w;
      pnpk[cb].x = pk2(n0, n1); pnpk[cb].y = pk2(n2, n3);
    }
#pragma unroll
    for (int fk = 0; fk < 4; ++fk) {
      uint4 u;
      u.x = pnpk[2 * fk].x;     u.y = pnpk[2 * fk].y;
      u.z = pnpk[2 * fk + 1].x; u.w = pnpk[2 * fk + 1].y;
      __builtin_memcpy(&pnf[rb][fk], &u, 16);
    }
  }
  __syncthreads();  // W1[0] landed

  // ---- MLP: 4 chunks of 128 hidden; single-buffer staged W ----
  f32x4 acc2[2][8];
#pragma unroll
  for (int rb = 0; rb < 2; ++rb)
#pragma unroll
    for (int cb = 0; cb < 8; ++cb) acc2[rb][cb] = fz;

  for (int ch = 0; ch < 4; ++ch) {
    // GEMM1 (reads buf = W1[ch], k-permuted)
    bf16x8 hf[2][4];
#pragma unroll
    for (int fk = 0; fk < 4; ++fk) {
      uint2 hpk[2][2];
#pragma unroll
      for (int cbl = 0; cbl < 2; ++cbl) {
        const int cb = fk * 2 + cbl;
        f32x4 hacc[2] = {fz, fz};
#pragma unroll
        for (int kk = 0; kk < 4; ++kk) {
          const bf16x8 w1f = *(const bf16x8*)(
              buf + SWZ(cb * 16 + lane16, kk * 64 + g16 * 16));
          hacc[0] = __builtin_amdgcn_mfma_f32_16x16x32_bf16(w1f, pnf[0][kk], hacc[0], 0, 0, 0);
          hacc[1] = __builtin_amdgcn_mfma_f32_16x16x32_bf16(w1f, pnf[1][kk], hacc[1], 0, 0, 0);
        }
        const int hcol = ch * 128 + cb * 16 + g16 * 4;
        const float4 bi = *(const float4*)(bp1 + hcol);
#pragma unroll
        for (int rb = 0; rb < 2; ++rb) {
          const float h0 = fmaxf(hacc[rb][0] + bi.x, 0.f);
          const float h1 = fmaxf(hacc[rb][1] + bi.y, 0.f);
          const float h2 = fmaxf(hacc[rb][2] + bi.z, 0.f);
          const float h3 = fmaxf(hacc[rb][3] + bi.w, 0.f);
          hpk[rb][cbl].x = pk2(h0, h1); hpk[rb][cbl].y = pk2(h2, h3);
        }
      }
#pragma unroll
      for (int rb = 0; rb < 2; ++rb) {
        uint4 u;
        u.x = hpk[rb][0].x; u.y = hpk[rb][0].y;
        u.z = hpk[rb][1].x; u.w = hpk[rb][1].y;
        __builtin_memcpy(&hf[rb][fk], &u, 16);
      }
    }
    __syncthreads();  // GEMM1 reads done
    stage_w32k(Wp2b, 512, ch * 128, buf, w, l);  // W2[ch] -> buf
    __syncthreads();  // W2[ch] landed
    // GEMM2 (reads buf = W2[ch], k-permuted)
#pragma unroll
    for (int cb = 0; cb < 8; ++cb) {
#pragma unroll
      for (int kk = 0; kk < 4; ++kk) {
        const bf16x8 w2f = *(const bf16x8*)(
            buf + SWZ(cb * 16 + lane16, kk * 64 + g16 * 16));
        acc2[0][cb] = __builtin_amdgcn_mfma_f32_16x16x32_bf16(w2f, hf[0][kk], acc2[0][cb], 0, 0, 0);
        acc2[1][cb] = __builtin_amdgcn_mfma_f32_16x16x32_bf16(w2f, hf[1][kk], acc2[1][cb], 0, 0, 0);
      }
    }
    if (ch < 3) {
      __syncthreads();  // GEMM2 reads done
      stage_w32k(Wp1b + (size_t)(ch + 1) * 128 * 128, 128, 0, buf, w, l);
      __syncthreads();  // W1[ch+1] landed
    }
  }

  // ---- epilogue: out = P + acc2 + bp2 ----
#pragma unroll
  for (int rb = 0; rb < 2; ++rb) {
#pragma unroll
    for (int cb = 0; cb < 8; ++cb) {
      const int col0 = cb * 16 + g16 * 4;
      const float4 b2 = *(const float4*)(bp2 + col0);
      float4 o4;
      o4.x = acc2[rb][cb][0] + b2.x + bfl(Ppk[rb][cb].x);
      o4.y = acc2[rb][cb][1] + b2.y + bfh(Ppk[rb][cb].x);
      o4.z = acc2[rb][cb][2] + b2.z + bfl(Ppk[rb][cb].y);
      o4.w = acc2[rb][cb][3] + b2.w + bfh(Ppk[rb][cb].y);
      *(float4*)(pout + grow[rb] * 128 + col0) = o4;
    }
  }
}

// ---------------------------------------------------------------------------
extern "C" void kernel_launch(void* const* d_in, const int* in_sizes, int n_in,
                              void* d_out, int out_size, void* d_ws,
                              size_t ws_size, hipStream_t stream) {
  (void)in_sizes; (void)n_in; (void)out_size; (void)ws_size;
  const float* seq      = (const float*)d_in[0];
  const float* pair     = (const float*)d_in[1];
  const float* ln_p2s_g = (const float*)d_in[2];
  const float* ln_p2s_b = (const float*)d_in[3];
  const float* W_p2s    = (const float*)d_in[4];
  const float* ln1_g    = (const float*)d_in[5];
  const float* ln1_b    = (const float*)d_in[6];
  const float* Wqkv     = (const float*)d_in[7];
  const float* Wo       = (const float*)d_in[8];
  const float* bo       = (const float*)d_in[9];
  const float* Wg       = (const float*)d_in[10];
  const float* bg       = (const float*)d_in[11];
  const float* ln_s_g   = (const float*)d_in[12];
  const float* ln_s_b   = (const float*)d_in[13];
  const float* Wm1      = (const float*)d_in[14];
  const float* bm1      = (const float*)d_in[15];
  const float* Wm2      = (const float*)d_in[16];
  const float* bm2      = (const float*)d_in[17];
  const float* ln_sp_g  = (const float*)d_in[18];
  const float* ln_sp_b  = (const float*)d_in[19];
  const float* Wsp      = (const float*)d_in[20];
  const float* bsp      = (const float*)d_in[21];
  const float* Wspo     = (const float*)d_in[22];
  const float* bspo     = (const float*)d_in[23];
  const float* ln_mp_g  = (const float*)d_in[24];
  const float* ln_mp_b  = (const float*)d_in[25];
  const float* Wp1      = (const float*)d_in[26];
  const float* bp1      = (const float*)d_in[27];
  const float* Wp2      = (const float*)d_in[28];
  const float* bp2      = (const float*)d_in[29];

  float* out_s = (float*)d_out;            // 512*1024
  float* out_p = out_s + 512 * 1024;       // 512*512*128

  // ---- workspace layout (float offsets) ----
  float* ws = (float*)d_ws;
  ushort_t* y_b = (ushort_t*)ws;                          // 262144 f
  ushort_t* t_b = (ushort_t*)(ws + 262144);               // 1048576 f (512x4096)
  float* s1  = ws + 262144 + 1048576;                     // 524288 f
  ushort_t* ob  = (ushort_t*)(s1 + 524288);               // 262144 f
  ushort_t* h1b = (ushort_t*)(s1 + 524288 + 262144);      // 1048576 f
  float* spb = s1 + 524288 + 262144 + 1048576;            // 65536 f
  ushort_t* wspo_b = (ushort_t*)(spb + 65536);            // 8192 f
  ushort_t* wp1_b  = (ushort_t*)(spb + 65536 + 8192);     // 32768 f
  ushort_t* wp2_b  = (ushort_t*)(spb + 65536 + 40960);    // 32768 f
  float* bias_cat  = spb + 65536 + 73728;                 // 4096 f

  // d_out p-section scratch (consumed before pairfuse writes)
  ushort_t* biasTb = (ushort_t*)out_p;                 // 8388608 ush (16 MB)
  ushort_t* wq_b  = (ushort_t*)(out_p + 8388608);      // 3145728 ush (Wqkv)
  ushort_t* wg_b  = wq_b + 3145728;                    // 1048576 (Wg, contiguous)
  ushort_t* wo_b  = wg_b + 1048576;
  ushort_t* wm1_b = wo_b + 1048576;
  ushort_t* wm2_b = wm1_b + 4194304;
  ushort_t* wsp_b = wm2_b + 4194304;

  cvt9_kernel<<<6808, 256, 0, stream>>>(Wqkv, wq_b, Wg, wg_b, Wo, wo_b,
                                        Wm1, wm1_b, Wm2, wm2_b, Wsp, wsp_b,
                                        Wspo, wspo_b, Wp1, wp1_b, Wp2, wp2_b,
                                        bg, bias_cat);
  ln1024b_kernel<<<512, 256, 0, stream>>>(seq, ln1_g, ln1_b, y_b);
  // fused qkv+gate GEMM: B = [Wqkv ; Wg] (contiguous), N = 4096
  gemm_mfma_kernel<1, 0, 0, 1><<<dim3(32, 8), 256, 0, stream>>>(
      y_b, wq_b, bias_cat, nullptr, nullptr, t_b, 512, 4096, 1024);
  p2s_mfma_kernel<<<2048, 256, 0, stream>>>(pair, ln_p2s_g, ln_p2s_b, W_p2s,
                                            biasTb);
  attn_kernel<<<dim3(8, 32), 256, 0, stream>>>(t_b, biasTb, ob);
  gemm_mfma_kernel<1, 0, 1, 0><<<dim3(8, 8), 256, 0, stream>>>(
      ob, wo_b, bo, seq, s1, nullptr, 512, 1024, 1024);
  ln1024b_kernel<<<512, 256, 0, stream>>>(s1, ln_s_g, ln_s_b, y_b);
  gemm_mfma_kernel<1, 1, 0, 1><<<dim3(32, 8), 256, 0, stream>>>(
      y_b, wm1_b, bm1, nullptr, nullptr, h1b, 512, 4096, 1024);
  gemm_mfma_kernel<1, 0, 1, 0><<<dim3(8, 8), 256, 0, stream>>>(
      h1b, wm2_b, bm2, s1, out_s, nullptr, 512, 1024, 4096);
  ln1024b_kernel<<<512, 256, 0, stream>>>(out_s, ln_sp_g, ln_sp_b, y_b);
  gemm_mfma_kernel<1, 0, 0, 0><<<dim3(1, 8), 256, 0, stream>>>(
      y_b, wsp_b, bsp, nullptr, spb, nullptr, 512, 128, 1024);
  pairfuse64_kernel<<<2048, 256, 0, stream>>>(spb, wspo_b, bspo, pair,
                                              ln_mp_g, ln_mp_b, wp1_b, bp1,
                                              wp2_b, bp2, out_p);
}

// Round 20
// 376.103 us; speedup vs baseline: 1.1552x; 1.1552x over previous
//
#include <hip/hip_runtime.h>
#include <hip/hip_bf16.h>
#include <cstddef>

// ---------------------------------------------------------------------------
// TriangularSelfAttentionBlock R19: revert to best measured config (R14/R15,
// 376.8us): pairfuse 64KB async W double-buffer @ (256,2), k-permuted
// shuffle-free fragments, HW cvt_pk, fused qkv+gate, bf16 biasT, flash attn.
// L=512, SEQ_D=1024, PAIR_D=128, H=32, HW=32, INNER=64
// ---------------------------------------------------------------------------

#define L 512
#define SEQ_D 1024
#define PAIR_D 128
#define NH 32
#define HW 32

typedef short bf16x8 __attribute__((ext_vector_type(8)));
typedef float f32x4 __attribute__((ext_vector_type(4)));
typedef unsigned short ushort_t;

__device__ inline float wred_sum(float v) {
#pragma unroll
  for (int off = 32; off; off >>= 1) v += __shfl_xor(v, off, 64);
  return v;
}
// f32 -> bf16 (RNE) packed pair via HW instruction (a low, b high)
__device__ inline unsigned pk2(float a, float b) {
  unsigned r;
  asm("v_cvt_pk_bf16_f32 %0, %1, %2" : "=v"(r) : "v"(a), "v"(b));
  return r;
}
__device__ inline ushort_t bf1(float a) {
  unsigned r;
  asm("v_cvt_pk_bf16_f32 %0, %1, %2" : "=v"(r) : "v"(a), "v"(0.f));
  return (ushort_t)r;
}
__device__ inline float bfl(unsigned u) { return __uint_as_float(u << 16); }
__device__ inline float bfh(unsigned u) { return __uint_as_float(u & 0xffff0000u); }
__device__ inline float bfu(ushort_t u) { return __uint_as_float((unsigned)u << 16); }

// swizzled byte offset for [row][256B] LDS tiles
#define SWZ(row, kb) ((((row)) << 8) + ((kb) ^ (((row)&7) << 4)))
// swizzled byte offset for [row][128B] LDS tiles
#define SWZ64(row, kb) ((((row)) << 7) + ((kb) ^ (((row)&7) << 4)))

// ---- async stage 32KB weight tile (128 rows x 256B swizzled) via
// global_load_lds: linear LDS dest, inverse-swizzled per-lane global source.
__device__ __forceinline__ void stage_w32k(const ushort_t* __restrict__ src,
                                           int row_stride, int col_off,
                                           char* lds, int w, int l) {
#pragma unroll
  for (int i = 0; i < 8; ++i) {
    const int o = w * 8192 + i * 1024 + l * 16;
    const int row = o >> 8;
    const int kb = (o & 255) ^ (((row) & 7) << 4);
    const ushort_t* g = src + (size_t)row * row_stride + col_off + (kb >> 1);
    __builtin_amdgcn_global_load_lds(
        (const __attribute__((address_space(1))) unsigned int*)g,
        (__attribute__((address_space(3))) unsigned int*)(lds + w * 8192 + i * 1024),
        16, 0, 0);
  }
}

// ---------------- fused f32->bf16 weight conversion + concat bias ----------
// Wp1/Wp2 written with each 128-wide k-chunk PERMUTED so GEMM fragments match
// the natural C-layout of the previous GEMM output. Blocks >= 6792 build the
// concatenated qkv|gate bias vector.
__global__ __launch_bounds__(256) void cvt9_kernel(
    const float* __restrict__ s0, ushort_t* __restrict__ d0,
    const float* __restrict__ s1, ushort_t* __restrict__ d1,
    const float* __restrict__ s2, ushort_t* __restrict__ d2,
    const float* __restrict__ s3, ushort_t* __restrict__ d3,
    const float* __restrict__ s4, ushort_t* __restrict__ d4,
    const float* __restrict__ s5, ushort_t* __restrict__ d5,
    const float* __restrict__ s6, ushort_t* __restrict__ d6,
    const float* __restrict__ s7, ushort_t* __restrict__ d7,
    const float* __restrict__ s8, ushort_t* __restrict__ d8,
    const float* __restrict__ bgate, float* __restrict__ bias_cat) {
  const int b = blockIdx.x;
  if (b >= 6792) {
    const int i = (b - 6792) * 256 + threadIdx.x;
    bias_cat[i] = (i < 3072) ? 0.f : bgate[i - 3072];
    return;
  }
  if (b >= 6728) {
    const float* s; ushort_t* d; int base, rowlen;
    if (b < 6760) { s = s7; d = d7; base = b - 6728; rowlen = 128; }
    else          { s = s8; d = d8; base = b - 6760; rowlen = 512; }
    const int i = base * 256 + threadIdx.x;
    float4 a = ((const float4*)s)[2 * i], c = ((const float4*)s)[2 * i + 1];
    const int fe = i * 8;
    const int row = fe / rowlen;
    const int fk = fe % rowlen;
    const int ch = fk >> 7, k0 = fk & 127;
    const int kk = k0 >> 5, r0 = k0 & 31;
    const int hi = (r0 >> 4) & 1, g16a = (r0 >> 2) & 3;
    const int p1 = kk * 32 + g16a * 8 + hi * 4;
    ushort_t* dst = d + (size_t)row * rowlen + ch * 128;
    uint2 w1; w1.x = pk2(a.x, a.y); w1.y = pk2(a.z, a.w);
    uint2 w2; w2.x = pk2(c.x, c.y); w2.y = pk2(c.z, c.w);
    *(uint2*)(dst + p1) = w1;
    *(uint2*)(dst + p1 + 8) = w2;
    return;
  }
  const float* s; ushort_t* d; int base;
  if (b < 1536)      { s = s0; d = d0; base = b; }
  else if (b < 2048) { s = s1; d = d1; base = b - 1536; }
  else if (b < 2560) { s = s2; d = d2; base = b - 2048; }
  else if (b < 4608) { s = s3; d = d3; base = b - 2560; }
  else if (b < 6656) { s = s4; d = d4; base = b - 4608; }
  else if (b < 6720) { s = s5; d = d5; base = b - 6656; }
  else               { s = s6; d = d6; base = b - 6720; }
  const int i = base * 256 + threadIdx.x;
  float4 a = ((const float4*)s)[2 * i], c = ((const float4*)s)[2 * i + 1];
  uint4 w;
  w.x = pk2(a.x, a.y); w.y = pk2(a.z, a.w);
  w.z = pk2(c.x, c.y); w.w = pk2(c.z, c.w);
  ((uint4*)d)[i] = w;
}

// ---------------- LayerNorm 1024 -> bf16 out -------------------------------
__global__ __launch_bounds__(256) void ln1024b_kernel(
    const float* __restrict__ in, const float* __restrict__ g,
    const float* __restrict__ b, ushort_t* __restrict__ out) {
  const int row = blockIdx.x;
  const int tid = threadIdx.x;
  float4 v = ((const float4*)(in + (size_t)row * SEQ_D))[tid];
  float s = v.x + v.y + v.z + v.w;
  float s2 = v.x * v.x + v.y * v.y + v.z * v.z + v.w * v.w;
  __shared__ float red[8];
  const int lane = tid & 63, wid = tid >> 6;
  s = wred_sum(s);
  s2 = wred_sum(s2);
  if (lane == 0) { red[wid] = s; red[4 + wid] = s2; }
  __syncthreads();
  s = red[0] + red[1] + red[2] + red[3];
  s2 = red[4] + red[5] + red[6] + red[7];
  const float mean = s * (1.0f / SEQ_D);
  const float var = s2 * (1.0f / SEQ_D) - mean * mean;
  const float rstd = rsqrtf(var + 1e-5f);
  float4 gv = ((const float4*)g)[tid];
  float4 bv = ((const float4*)b)[tid];
  const float o0 = (v.x - mean) * rstd * gv.x + bv.x;
  const float o1 = (v.y - mean) * rstd * gv.y + bv.y;
  const float o2 = (v.z - mean) * rstd * gv.z + bv.z;
  const float o3 = (v.w - mean) * rstd * gv.w + bv.w;
  uint2 pkd; pkd.x = pk2(o0, o1); pkd.y = pk2(o2, o3);
  ((uint2*)(out + (size_t)row * SEQ_D))[tid] = pkd;
}

// ---------------- MFMA GEMM: C[M][N] = A[M][K](bf16) @ B[N][K]^T(bf16) -----
template <int BIAS, int RELU, int RES, int OBF16>
__global__ __launch_bounds__(256, 2) void gemm_mfma_kernel(
    const ushort_t* __restrict__ A, const ushort_t* __restrict__ B,
    const float* __restrict__ bias, const float* __restrict__ res,
    float* __restrict__ C, ushort_t* __restrict__ Cb, int M, int N, int K) {
  __shared__ __align__(16) char smem[24576];
  char* Ab = smem;
  char* Bb = smem + 8192;
  const int tid = threadIdx.x;
  const int l = tid & 63, w = tid >> 6;
  const int wr = w >> 1, wc = w & 1;
  const int lane16 = l & 15, g16 = l >> 4;
  const int bm = blockIdx.y * 64, bn = blockIdx.x * 128;
  const f32x4 fz = {0.f, 0.f, 0.f, 0.f};
  f32x4 acc[4][2];
#pragma unroll
  for (int i = 0; i < 4; ++i)
#pragma unroll
    for (int j = 0; j < 2; ++j) acc[i][j] = fz;

  for (int k0 = 0; k0 < K; k0 += 64) {
    __syncthreads();
#pragma unroll
    for (int u = 0; u < 2; ++u) {
      const int slot = u * 256 + tid;
      const int row = slot >> 3, sl = slot & 7;
      bf16x8 v = *(const bf16x8*)(A + (size_t)(bm + row) * K + k0 + sl * 8);
      *(bf16x8*)(Ab + SWZ64(row, sl * 16)) = v;
    }
#pragma unroll
    for (int u = 0; u < 4; ++u) {
      const int slot = u * 256 + tid;
      const int row = slot >> 3, sl = slot & 7;
      bf16x8 v = *(const bf16x8*)(B + (size_t)(bn + row) * K + k0 + sl * 8);
      *(bf16x8*)(Bb + SWZ64(row, sl * 16)) = v;
    }
    __syncthreads();
#pragma unroll
    for (int kk = 0; kk < 2; ++kk) {
      const int kb = kk * 64 + g16 * 16;
      bf16x8 af[2], bf[4];
#pragma unroll
      for (int rb = 0; rb < 2; ++rb) {
        const int row = wr * 32 + rb * 16 + lane16;
        af[rb] = *(const bf16x8*)(Ab + SWZ64(row, kb));
      }
#pragma unroll
      for (int cb = 0; cb < 4; ++cb) {
        const int row = wc * 64 + cb * 16 + lane16;
        bf[cb] = *(const bf16x8*)(Bb + SWZ64(row, kb));
      }
#pragma unroll
      for (int cb = 0; cb < 4; ++cb)
#pragma unroll
        for (int rb = 0; rb < 2; ++rb)
          acc[cb][rb] = __builtin_amdgcn_mfma_f32_16x16x32_bf16(
              bf[cb], af[rb], acc[cb][rb], 0, 0, 0);
    }
  }
#pragma unroll
  for (int cb = 0; cb < 4; ++cb) {
    const int col0 = bn + wc * 64 + cb * 16 + g16 * 4;
    float4 bi = make_float4(0.f, 0.f, 0.f, 0.f);
    if (BIAS) bi = *(const float4*)(bias + col0);
#pragma unroll
    for (int rb = 0; rb < 2; ++rb) {
      const int row = bm + wr * 32 + rb * 16 + lane16;
      f32x4 v = acc[cb][rb];
      v[0] += bi.x; v[1] += bi.y; v[2] += bi.z; v[3] += bi.w;
      if (RELU) {
        v[0] = fmaxf(v[0], 0.f); v[1] = fmaxf(v[1], 0.f);
        v[2] = fmaxf(v[2], 0.f); v[3] = fmaxf(v[3], 0.f);
      }
      if (RES) {
        const float4 r4 = *(const float4*)(res + (size_t)row * N + col0);
        v[0] += r4.x; v[1] += r4.y; v[2] += r4.z; v[3] += r4.w;
      }
      if (OBF16) {
        uint2 pkd; pkd.x = pk2(v[0], v[1]); pkd.y = pk2(v[2], v[3]);
        *(uint2*)(Cb + (size_t)row * N + col0) = pkd;
      } else {
        float4 o4; o4.x = v[0]; o4.y = v[1]; o4.z = v[2]; o4.w = v[3];
        *(float4*)(C + (size_t)row * N + col0) = o4;
      }
    }
  }
}

// ---------------- PairToSequence via MFMA (bf16 biasT out) -----------------
__global__ __launch_bounds__(256) void p2s_mfma_kernel(
    const float* __restrict__ pair, const float* __restrict__ g,
    const float* __restrict__ b, const float* __restrict__ W,
    ushort_t* __restrict__ biasTb) {
  __shared__ __align__(16) char pnb[32768];
  __shared__ __align__(16) char wls[8192];
  const int tid = threadIdx.x;
  const int l = tid & 63, w = tid >> 6;
  const int lane16 = l & 15, g16 = l >> 4;
  const size_t r0 = (size_t)blockIdx.x * 128;
  const int i_idx = (int)(r0 >> 9), j0 = (int)(r0 & 511);
#pragma unroll
  for (int u = 0; u < 2; ++u) {
    const int slot = u * 256 + tid;
    const int row = slot >> 4, sl = slot & 15;
    const float4 v0 = *(const float4*)(W + (size_t)row * 128 + sl * 8);
    const float4 v1 = *(const float4*)(W + (size_t)row * 128 + sl * 8 + 4);
    uint4 wv; wv.x = pk2(v0.x, v0.y); wv.y = pk2(v0.z, v0.w);
    wv.z = pk2(v1.x, v1.y); wv.w = pk2(v1.z, v1.w);
    *(uint4*)(wls + SWZ(row, sl * 16)) = wv;
  }
  {
    const int l32 = tid & 31, rg = tid >> 5;
    const float4 gv = *(const float4*)(g + l32 * 4);
    const float4 bv = *(const float4*)(b + l32 * 4);
#pragma unroll
    for (int it = 0; it < 16; ++it) {
      const int r = it * 8 + rg;
      const float4 v = *(const float4*)(pair + (r0 + r) * 128 + l32 * 4);
      float s = v.x + v.y + v.z + v.w;
      float s2 = v.x * v.x + v.y * v.y + v.z * v.z + v.w * v.w;
#pragma unroll
      for (int off = 1; off < 32; off <<= 1) {
        s += __shfl_xor(s, off, 64);
        s2 += __shfl_xor(s2, off, 64);
      }
      const float mean = s * (1.0f / 128.0f);
      const float rstd = rsqrtf(s2 * (1.0f / 128.0f) - mean * mean + 1e-5f);
      const float n0 = (v.x - mean) * rstd * gv.x + bv.x;
      const float n1 = (v.y - mean) * rstd * gv.y + bv.y;
      const float n2 = (v.z - mean) * rstd * gv.z + bv.z;
      const float n3 = (v.w - mean) * rstd * gv.w + bv.w;
      uint2 pkd; pkd.x = pk2(n0, n1); pkd.y = pk2(n2, n3);
      *(uint2*)(pnb + SWZ(r, l32 * 8)) = pkd;
    }
  }
  __syncthreads();
  const f32x4 fz = {0.f, 0.f, 0.f, 0.f};
  f32x4 a2[2][2];
#pragma unroll
  for (int i = 0; i < 2; ++i)
#pragma unroll
    for (int j = 0; j < 2; ++j) a2[i][j] = fz;
#pragma unroll
  for (int kk = 0; kk < 4; ++kk) {
    bf16x8 wf[2], pf[2];
#pragma unroll
    for (int hb = 0; hb < 2; ++hb)
      wf[hb] = *(const bf16x8*)(wls + SWZ(hb * 16 + lane16, kk * 64 + g16 * 16));
#pragma unroll
    for (int rb = 0; rb < 2; ++rb)
      pf[rb] = *(const bf16x8*)(pnb + SWZ(w * 32 + rb * 16 + lane16, kk * 64 + g16 * 16));
#pragma unroll
    for (int hb = 0; hb < 2; ++hb)
#pragma unroll
      for (int rb = 0; rb < 2; ++rb)
        a2[hb][rb] = __builtin_amdgcn_mfma_f32_16x16x32_bf16(
            wf[hb], pf[rb], a2[hb][rb], 0, 0, 0);
  }
#pragma unroll
  for (int hb = 0; hb < 2; ++hb)
#pragma unroll
    for (int rb = 0; rb < 2; ++rb) {
      const int j = j0 + w * 32 + rb * 16 + lane16;
#pragma unroll
      for (int qq = 0; qq < 4; ++qq) {
        const int hh = hb * 16 + g16 * 4 + qq;
        biasTb[((size_t)hh * 512 + i_idx) * 512 + j] = bf1(a2[hb][rb][qq]);
      }
    }
}

// ---------------- fused attention + gate: ob = sig(g)*softmax(S)V ----------
// tb row layout: [qkv 3072 | gate 1024], stride 4096 bf16.
__global__ __launch_bounds__(256) void attn_kernel(
    const ushort_t* __restrict__ tb, const ushort_t* __restrict__ biasTb,
    ushort_t* __restrict__ ob) {
  __shared__ __align__(16) ushort_t Vt[32][80];
  const int tid = threadIdx.x;
  const int l = tid & 63, wq = tid >> 6;
  const int lane16 = l & 15, g16 = l >> 4;
  const int h = blockIdx.y;
  const int q = blockIdx.x * 64 + wq * 16 + lane16;
  const float scale = 0.17677669529663689f;
  const bf16x8 qf = *(const bf16x8*)(tb + (size_t)q * 4096 + h * 96 + g16 * 8);
  const ushort_t* brow = biasTb + ((size_t)h * 512 + q) * 512;
  float m = -3e38f, lsum = 0.f;
  const f32x4 fz = {0.f, 0.f, 0.f, 0.f};
  f32x4 accp[2] = {fz, fz};
  for (int kt = 0; kt < 512; kt += 64) {
    {
      const int kr = tid >> 2, cc = tid & 3;
      bf16x8 vv = *(const bf16x8*)(tb + (size_t)(kt + kr) * 4096 + h * 96 + 64 + cc * 8);
#pragma unroll
      for (int u = 0; u < 8; ++u) Vt[cc * 8 + u][kr] = (ushort_t)vv[u];
    }
    __syncthreads();
    f32x4 st[4];
#pragma unroll
    for (int kb = 0; kb < 4; ++kb) {
      const bf16x8 kf = *(const bf16x8*)(
          tb + (size_t)(kt + kb * 16 + lane16) * 4096 + h * 96 + 32 + g16 * 8);
      st[kb] = __builtin_amdgcn_mfma_f32_16x16x32_bf16(kf, qf, fz, 0, 0, 0);
      const ushort4 bv = *(const ushort4*)(brow + kt + kb * 16 + g16 * 4);
      st[kb][0] = st[kb][0] * scale + bfu(bv.x);
      st[kb][1] = st[kb][1] * scale + bfu(bv.y);
      st[kb][2] = st[kb][2] * scale + bfu(bv.z);
      st[kb][3] = st[kb][3] * scale + bfu(bv.w);
    }
    float tm = st[0][0];
#pragma unroll
    for (int kb = 0; kb < 4; ++kb)
#pragma unroll
      for (int qq = 0; qq < 4; ++qq) tm = fmaxf(tm, st[kb][qq]);
    tm = fmaxf(tm, __shfl_xor(tm, 16, 64));
    tm = fmaxf(tm, __shfl_xor(tm, 32, 64));
    const float mn = fmaxf(m, tm);
    const float corr = __expf(m - mn);
    m = mn;
    lsum *= corr;
#pragma unroll
    for (int ct = 0; ct < 2; ++ct) {
      accp[ct][0] *= corr; accp[ct][1] *= corr;
      accp[ct][2] *= corr; accp[ct][3] *= corr;
    }
#pragma unroll
    for (int kb = 0; kb < 4; ++kb)
#pragma unroll
      for (int qq = 0; qq < 4; ++qq) {
        const float e = __expf(st[kb][qq] - mn);
        st[kb][qq] = e;
        lsum += e;
      }
    const int src0 = lane16 + ((l & 16) << 1);
    const int src1 = src0 + 16;
    const bool hi = (l & 32) != 0;
#pragma unroll
    for (int kk = 0; kk < 2; ++kk) {
      float lo4[4], hi4[4];
#pragma unroll
      for (int qq = 0; qq < 4; ++qq) {
        const float a0 = __shfl(st[kk * 2][qq], src0, 64);
        const float a1 = __shfl(st[kk * 2][qq], src1, 64);
        const float b0 = __shfl(st[kk * 2 + 1][qq], src0, 64);
        const float b1 = __shfl(st[kk * 2 + 1][qq], src1, 64);
        lo4[qq] = hi ? b0 : a0;
        hi4[qq] = hi ? b1 : a1;
      }
      uint4 pu;
      pu.x = pk2(lo4[0], lo4[1]); pu.y = pk2(lo4[2], lo4[3]);
      pu.z = pk2(hi4[0], hi4[1]); pu.w = pk2(hi4[2], hi4[3]);
      bf16x8 pf;
      __builtin_memcpy(&pf, &pu, 16);
#pragma unroll
      for (int ct = 0; ct < 2; ++ct) {
        const bf16x8 vf = *(const bf16x8*)&Vt[ct * 16 + lane16][kk * 32 + g16 * 8];
        accp[ct] = __builtin_amdgcn_mfma_f32_16x16x32_bf16(vf, pf, accp[ct], 0, 0, 0);
      }
    }
    __syncthreads();
  }
  lsum += __shfl_xor(lsum, 16, 64);
  lsum += __shfl_xor(lsum, 32, 64);
  const float inv = 1.0f / lsum;
#pragma unroll
  for (int ct = 0; ct < 2; ++ct) {
    const int col = h * 32 + ct * 16 + g16 * 4;
    const ushort4 gv = *(const ushort4*)(tb + (size_t)q * 4096 + 3072 + col);
    float4 o4;
    o4.x = accp[ct][0] * inv * (1.0f / (1.0f + __expf(-bfu(gv.x))));
    o4.y = accp[ct][1] * inv * (1.0f / (1.0f + __expf(-bfu(gv.y))));
    o4.z = accp[ct][2] * inv * (1.0f / (1.0f + __expf(-bfu(gv.z))));
    o4.w = accp[ct][3] * inv * (1.0f / (1.0f + __expf(-bfu(gv.w))));
    uint2 pkd; pkd.x = pk2(o4.x, o4.y); pkd.y = pk2(o4.z, o4.w);
    *(uint2*)(ob + (size_t)q * SEQ_D + col) = pkd;
  }
}

// ---------------- fused SequenceToPair + pair MLP (rb=2, async W DMA,
// shuffle-free via k-permuted W1/W2) — proven best configuration ------------
__global__ __launch_bounds__(256, 2) void pairfuse64_kernel(
    const float* __restrict__ spb, const ushort_t* __restrict__ Wspob,
    const float* __restrict__ bspo, const float* __restrict__ pairw,
    const float* __restrict__ lng, const float* __restrict__ lnb,
    const ushort_t* __restrict__ Wp1b, const float* __restrict__ bp1,
    const ushort_t* __restrict__ Wp2b, const float* __restrict__ bp2,
    float* __restrict__ pout) {
  __shared__ __align__(16) char Wbuf[65536];
  char* buf0 = Wbuf;
  char* buf1 = Wbuf + 32768;
  const int tid = threadIdx.x;
  const int l = tid & 63, w = tid >> 6;
  const int lane16 = l & 15, g16 = l >> 4;
  const size_t r0 = (size_t)blockIdx.x * 128;
  const int i_idx = (int)(r0 >> 9), j0 = (int)(r0 & 511);
  size_t grow[2];
  grow[0] = r0 + w * 32 + lane16;
  grow[1] = grow[0] + 16;

  // ---- issue Wspo -> buf0, W1[0] -> buf1 (async; drained at first sync) ---
  stage_w32k(Wspob, 128, 0, buf0, w, l);
  stage_w32k(Wp1b, 128, 0, buf1, w, l);

  // ---- build X A-frags in registers: X = [qh*kh | qh-kh] ----
  bf16x8 xf[2][4];
  {
    const float* krow = spb + (size_t)i_idx * 128 + 64;
#pragma unroll
    for (int rb = 0; rb < 2; ++rb) {
      const float* qrow = spb + (size_t)(j0 + w * 32 + rb * 16 + lane16) * 128;
#pragma unroll
      for (int kk = 0; kk < 4; ++kk) {
        const int c = ((kk & 1) << 5) + g16 * 8;
        const float4 q0 = *(const float4*)(qrow + c);
        const float4 q1 = *(const float4*)(qrow + c + 4);
        const float4 k0 = *(const float4*)(krow + c);
        const float4 k1 = *(const float4*)(krow + c + 4);
        uint4 u;
        if (kk < 2) {
          u.x = pk2(q0.x * k0.x, q0.y * k0.y);
          u.y = pk2(q0.z * k0.z, q0.w * k0.w);
          u.z = pk2(q1.x * k1.x, q1.y * k1.y);
          u.w = pk2(q1.z * k1.z, q1.w * k1.w);
        } else {
          u.x = pk2(q0.x - k0.x, q0.y - k0.y);
          u.y = pk2(q0.z - k0.z, q0.w - k0.w);
          u.z = pk2(q1.x - k1.x, q1.y - k1.y);
          u.w = pk2(q1.z - k1.z, q1.w - k1.w);
        }
        __builtin_memcpy(&xf[rb][kk], &u, 16);
      }
    }
  }
  __syncthreads();  // Wspo + W1[0] landed

  // ---- GEMM0: acc[rb][cb] = X @ Wspo^T (reads buf0) ----
  const f32x4 fz = {0.f, 0.f, 0.f, 0.f};
  f32x4 acc[2][8];
#pragma unroll
  for (int rb = 0; rb < 2; ++rb)
#pragma unroll
    for (int cb = 0; cb < 8; ++cb) acc[rb][cb] = fz;
#pragma unroll
  for (int cb = 0; cb < 8; ++cb) {
#pragma unroll
    for (int kk = 0; kk < 4; ++kk) {
      const bf16x8 wf = *(const bf16x8*)(
          buf0 + SWZ(cb * 16 + lane16, kk * 64 + g16 * 16));
      acc[0][cb] = __builtin_amdgcn_mfma_f32_16x16x32_bf16(wf, xf[0][kk], acc[0][cb], 0, 0, 0);
      acc[1][cb] = __builtin_amdgcn_mfma_f32_16x16x32_bf16(wf, xf[1][kk], acc[1][cb], 0, 0, 0);
    }
  }

  // ---- P = acc + bspo + pair; LN stats in-wave (per rb) ----
  uint2 Ppk[2][8];
  bf16x8 pnf[2][4];
#pragma unroll
  for (int rb = 0; rb < 2; ++rb) {
    float s = 0.f, s2 = 0.f;
#pragma unroll
    for (int cb = 0; cb < 8; ++cb) {
      const int col0 = cb * 16 + g16 * 4;
      const float4 bs = *(const float4*)(bspo + col0);
      const float4 pw = *(const float4*)(pairw + grow[rb] * 128 + col0);
      acc[rb][cb][0] += bs.x + pw.x; acc[rb][cb][1] += bs.y + pw.y;
      acc[rb][cb][2] += bs.z + pw.z; acc[rb][cb][3] += bs.w + pw.w;
      s += acc[rb][cb][0] + acc[rb][cb][1] + acc[rb][cb][2] + acc[rb][cb][3];
      s2 += acc[rb][cb][0] * acc[rb][cb][0] + acc[rb][cb][1] * acc[rb][cb][1] +
            acc[rb][cb][2] * acc[rb][cb][2] + acc[rb][cb][3] * acc[rb][cb][3];
      Ppk[rb][cb].x = pk2(acc[rb][cb][0], acc[rb][cb][1]);
      Ppk[rb][cb].y = pk2(acc[rb][cb][2], acc[rb][cb][3]);
    }
    s += __shfl_xor(s, 16, 64);  s += __shfl_xor(s, 32, 64);
    s2 += __shfl_xor(s2, 16, 64); s2 += __shfl_xor(s2, 32, 64);
    const float mean = s * (1.0f / 128.0f);
    const float rstd = rsqrtf(s2 * (1.0f / 128.0f) - mean * mean + 1e-5f);
    uint2 pnpk[8];
#pragma unroll
    for (int cb = 0; cb < 8; ++cb) {
      const int col0 = cb * 16 + g16 * 4;
      const float4 gv = *(const float4*)(lng + col0);
      const float4 bv = *(const float4*)(lnb + col0);
      const float n0 = (acc[rb][cb][0] - mean) * rstd * gv.x + bv.x;
      const float n1 = (acc[rb][cb][1] - mean) * rstd * gv.y + bv.y;
      const float n2 = (acc[rb][cb][2] - mean) * rstd * gv.z + bv.z;
      const float n3 = (acc[rb][cb][3] - mean) * rstd * gv.w + bv.w;
      pnpk[cb].x = pk2(n0, n1); pnpk[cb].y = pk2(n2, n3);
    }
#pragma unroll
    for (int fk = 0; fk < 4; ++fk) {
      uint4 u;
      u.x = pnpk[2 * fk].x;     u.y = pnpk[2 * fk].y;
      u.z = pnpk[2 * fk + 1].x; u.w = pnpk[2 * fk + 1].y;
      __builtin_memcpy(&pnf[rb][fk], &u, 16);
    }
  }

  // ---- MLP: 4 chunks of 128 hidden; double-buffered async W staging ----
  f32x4 acc2[2][8];
#pragma unroll
  for (int rb = 0; rb < 2; ++rb)
#pragma unroll
    for (int cb = 0; cb < 8; ++cb) acc2[rb][cb] = fz;

  for (int ch = 0; ch < 4; ++ch) {
    __syncthreads();  // all waves done reading buf0; W1[ch] landed in buf1
    stage_w32k(Wp2b, 512, ch * 128, buf0, w, l);  // async W2[ch] -> buf0
    // GEMM1 (reads buf1 = W1[ch], k-permuted) overlaps the W2 loads
    bf16x8 hf[2][4];
#pragma unroll
    for (int fk = 0; fk < 4; ++fk) {
      uint2 hpk[2][2];
#pragma unroll
      for (int cbl = 0; cbl < 2; ++cbl) {
        const int cb = fk * 2 + cbl;
        f32x4 hacc[2] = {fz, fz};
#pragma unroll
        for (int kk = 0; kk < 4; ++kk) {
          const bf16x8 w1f = *(const bf16x8*)(
              buf1 + SWZ(cb * 16 + lane16, kk * 64 + g16 * 16));
          hacc[0] = __builtin_amdgcn_mfma_f32_16x16x32_bf16(w1f, pnf[0][kk], hacc[0], 0, 0, 0);
          hacc[1] = __builtin_amdgcn_mfma_f32_16x16x32_bf16(w1f, pnf[1][kk], hacc[1], 0, 0, 0);
        }
        const int hcol = ch * 128 + cb * 16 + g16 * 4;
        const float4 bi = *(const float4*)(bp1 + hcol);
#pragma unroll
        for (int rb = 0; rb < 2; ++rb) {
          const float h0 = fmaxf(hacc[rb][0] + bi.x, 0.f);
          const float h1 = fmaxf(hacc[rb][1] + bi.y, 0.f);
          const float h2 = fmaxf(hacc[rb][2] + bi.z, 0.f);
          const float h3 = fmaxf(hacc[rb][3] + bi.w, 0.f);
          hpk[rb][cbl].x = pk2(h0, h1); hpk[rb][cbl].y = pk2(h2, h3);
        }
      }
#pragma unroll
      for (int rb = 0; rb < 2; ++rb) {
        uint4 u;
        u.x = hpk[rb][0].x; u.y = hpk[rb][0].y;
        u.z = hpk[rb][1].x; u.w = hpk[rb][1].y;
        __builtin_memcpy(&hf[rb][fk], &u, 16);
      }
    }
    __syncthreads();  // W2[ch] landed; all waves done reading buf1
    if (ch < 3) stage_w32k(Wp1b + (size_t)(ch + 1) * 128 * 128, 128, 0, buf1, w, l);
    // GEMM2 (reads buf0 = W2[ch], k-permuted) overlaps the next W1 loads
#pragma unroll
    for (int cb = 0; cb < 8; ++cb) {
#pragma unroll
      for (int kk = 0; kk < 4; ++kk) {
        const bf16x8 w2f = *(const bf16x8*)(
            buf0 + SWZ(cb * 16 + lane16, kk * 64 + g16 * 16));
        acc2[0][cb] = __builtin_amdgcn_mfma_f32_16x16x32_bf16(w2f, hf[0][kk], acc2[0][cb], 0, 0, 0);
        acc2[1][cb] = __builtin_amdgcn_mfma_f32_16x16x32_bf16(w2f, hf[1][kk], acc2[1][cb], 0, 0, 0);
      }
    }
  }

  // ---- epilogue: out = P + acc2 + bp2 ----
#pragma unroll
  for (int rb = 0; rb < 2; ++rb) {
#pragma unroll
    for (int cb = 0; cb < 8; ++cb) {
      const int col0 = cb * 16 + g16 * 4;
      const float4 b2 = *(const float4*)(bp2 + col0);
      float4 o4;
      o4.x = acc2[rb][cb][0] + b2.x + bfl(Ppk[rb][cb].x);
      o4.y = acc2[rb][cb][1] + b2.y + bfh(Ppk[rb][cb].x);
      o4.z = acc2[rb][cb][2] + b2.z + bfl(Ppk[rb][cb].y);
      o4.w = acc2[rb][cb][3] + b2.w + bfh(Ppk[rb][cb].y);
      *(float4*)(pout + grow[rb] * 128 + col0) = o4;
    }
  }
}

// ---------------------------------------------------------------------------
extern "C" void kernel_launch(void* const* d_in, const int* in_sizes, int n_in,
                              void* d_out, int out_size, void* d_ws,
                              size_t ws_size, hipStream_t stream) {
  (void)in_sizes; (void)n_in; (void)out_size; (void)ws_size;
  const float* seq      = (const float*)d_in[0];
  const float* pair     = (const float*)d_in[1];
  const float* ln_p2s_g = (const float*)d_in[2];
  const float* ln_p2s_b = (const float*)d_in[3];
  const float* W_p2s    = (const float*)d_in[4];
  const float* ln1_g    = (const float*)d_in[5];
  const float* ln1_b    = (const float*)d_in[6];
  const float* Wqkv     = (const float*)d_in[7];
  const float* Wo       = (const float*)d_in[8];
  const float* bo       = (const float*)d_in[9];
  const float* Wg       = (const float*)d_in[10];
  const float* bg       = (const float*)d_in[11];
  const float* ln_s_g   = (const float*)d_in[12];
  const float* ln_s_b   = (const float*)d_in[13];
  const float* Wm1      = (const float*)d_in[14];
  const float* bm1      = (const float*)d_in[15];
  const float* Wm2      = (const float*)d_in[16];
  const float* bm2      = (const float*)d_in[17];
  const float* ln_sp_g  = (const float*)d_in[18];
  const float* ln_sp_b  = (const float*)d_in[19];
  const float* Wsp      = (const float*)d_in[20];
  const float* bsp      = (const float*)d_in[21];
  const float* Wspo     = (const float*)d_in[22];
  const float* bspo     = (const float*)d_in[23];
  const float* ln_mp_g  = (const float*)d_in[24];
  const float* ln_mp_b  = (const float*)d_in[25];
  const float* Wp1      = (const float*)d_in[26];
  const float* bp1      = (const float*)d_in[27];
  const float* Wp2      = (const float*)d_in[28];
  const float* bp2      = (const float*)d_in[29];

  float* out_s = (float*)d_out;            // 512*1024
  float* out_p = out_s + 512 * 1024;       // 512*512*128

  // ---- workspace layout (float offsets) ----
  float* ws = (float*)d_ws;
  ushort_t* y_b = (ushort_t*)ws;                          // 262144 f
  ushort_t* t_b = (ushort_t*)(ws + 262144);               // 1048576 f (512x4096)
  float* s1  = ws + 262144 + 1048576;                     // 524288 f
  ushort_t* ob  = (ushort_t*)(s1 + 524288);               // 262144 f
  ushort_t* h1b = (ushort_t*)(s1 + 524288 + 262144);      // 1048576 f
  float* spb = s1 + 524288 + 262144 + 1048576;            // 65536 f
  ushort_t* wspo_b = (ushort_t*)(spb + 65536);            // 8192 f
  ushort_t* wp1_b  = (ushort_t*)(spb + 65536 + 8192);     // 32768 f
  ushort_t* wp2_b  = (ushort_t*)(spb + 65536 + 40960);    // 32768 f
  float* bias_cat  = spb + 65536 + 73728;                 // 4096 f

  // d_out p-section scratch (consumed before pairfuse writes)
  ushort_t* biasTb = (ushort_t*)out_p;                 // 8388608 ush (16 MB)
  ushort_t* wq_b  = (ushort_t*)(out_p + 8388608);      // 3145728 ush (Wqkv)
  ushort_t* wg_b  = wq_b + 3145728;                    // 1048576 (Wg, contiguous)
  ushort_t* wo_b  = wg_b + 1048576;
  ushort_t* wm1_b = wo_b + 1048576;
  ushort_t* wm2_b = wm1_b + 4194304;
  ushort_t* wsp_b = wm2_b + 4194304;

  cvt9_kernel<<<6808, 256, 0, stream>>>(Wqkv, wq_b, Wg, wg_b, Wo, wo_b,
                                        Wm1, wm1_b, Wm2, wm2_b, Wsp, wsp_b,
                                        Wspo, wspo_b, Wp1, wp1_b, Wp2, wp2_b,
                                        bg, bias_cat);
  ln1024b_kernel<<<512, 256, 0, stream>>>(seq, ln1_g, ln1_b, y_b);
  // fused qkv+gate GEMM: B = [Wqkv ; Wg] (contiguous), N = 4096
  gemm_mfma_kernel<1, 0, 0, 1><<<dim3(32, 8), 256, 0, stream>>>(
      y_b, wq_b, bias_cat, nullptr, nullptr, t_b, 512, 4096, 1024);
  p2s_mfma_kernel<<<2048, 256, 0, stream>>>(pair, ln_p2s_g, ln_p2s_b, W_p2s,
                                            biasTb);
  attn_kernel<<<dim3(8, 32), 256, 0, stream>>>(t_b, biasTb, ob);
  gemm_mfma_kernel<1, 0, 1, 0><<<dim3(8, 8), 256, 0, stream>>>(
      ob, wo_b, bo, seq, s1, nullptr, 512, 1024, 1024);
  ln1024b_kernel<<<512, 256, 0, stream>>>(s1, ln_s_g, ln_s_b, y_b);
  gemm_mfma_kernel<1, 1, 0, 1><<<dim3(32, 8), 256, 0, stream>>>(
      y_b, wm1_b, bm1, nullptr, nullptr, h1b, 512, 4096, 1024);
  gemm_mfma_kernel<1, 0, 1, 0><<<dim3(8, 8), 256, 0, stream>>>(
      h1b, wm2_b, bm2, s1, out_s, nullptr, 512, 1024, 4096);
  ln1024b_kernel<<<512, 256, 0, stream>>>(out_s, ln_sp_g, ln_sp_b, y_b);
  gemm_mfma_kernel<1, 0, 0, 0><<<dim3(1, 8), 256, 0, stream>>>(
      y_b, wsp_b, bsp, nullptr, spb, nullptr, 512, 128, 1024);
  pairfuse64_kernel<<<2048, 256, 0, stream>>>(spb, wspo_b, bspo, pair,
                                              ln_mp_g, ln_mp_b, wp1_b, bp1,
                                              wp2_b, bp2, out_p);
}